// Round 2
// baseline (330.023 us; speedup 1.0000x reference)
//
#include <hip/hip_runtime.h>
#include <hip/hip_bf16.h>

// PatchLoss for MI355X (gfx950) — three-kernel decomposition via workspace.
//
// loss = (1/(B*T^2)) * sum_{b,t,u} w[b,t,u] * (z2[b,t] + z2[b,u] - 2*G[b,t,u])
//   w = exp(-sum_k gt_dT^2 / (2 sigma_k^2)),  G[b] = z_b z_b^T,  z2 = ||z_bt||^2
//
// Round-1 counters (fused, 117us): MfmaUtil 5.5 / VALUBusy 9.2 / HBM 16.8% /
// Occ 36.5% -> latency-bound at 1 block/CU. Fix: decouple.
//   A: Gram+z2 -> ws   (512 blocks, 16 waves/CU, padded LDS: no bank conflicts)
//   B: stream gt_dT, fold with G/z2 (2048 blocks, 32 waves/CU, no barriers)
//   C: reduce 2048 partials -> out
// Fallback to the round-1 fused kernel if ws_size < ~39.5 MB.

typedef __attribute__((ext_vector_type(8))) __bf16 bf16x8;
typedef __attribute__((ext_vector_type(4))) float f32x4;

#define NB   256
#define TT   196
#define DD   768
#define TTT  (TT * TT)        // 38416
#define BK   32
#define NKS  (DD / BK)        // 24
#define ZPAD 40               // slab row stride (elems): 80 B = 20 banks -> conflict-free

// ---------------- Kernel A: batched Gram + z2 ----------------
// grid 512 = (b,s): 2 strips of 128 t-rows per b. 512 threads = 8 waves.
// Wave w owns A-rows [s*128 + w*16, +16), 13 u-fragments (u = j*16 + lane&15).

#define ATH 512

__device__ __forceinline__ bf16x8 pack8(const float4& a, const float4& b) {
    bf16x8 v;
    v[0] = (__bf16)a.x; v[1] = (__bf16)a.y; v[2] = (__bf16)a.z; v[3] = (__bf16)a.w;
    v[4] = (__bf16)b.x; v[5] = (__bf16)b.y; v[6] = (__bf16)b.z; v[7] = (__bf16)b.w;
    return v;
}
__device__ __forceinline__ float sq8(const float4& a, const float4& b) {
    return a.x*a.x + a.y*a.y + a.z*a.z + a.w*a.w
         + b.x*b.x + b.y*b.y + b.z*b.z + b.w*b.w;
}

__global__ __launch_bounds__(ATH)
void gram_kernel(const float* __restrict__ z,
                 float* __restrict__ G,
                 float* __restrict__ z2g)
{
    __shared__ __bf16 Zt[2][208][ZPAD];     // 2 x 16.25 KB

    // XCD swizzle: both strips of a given b land on the same XCD's L2.
    const int hw = blockIdx.x;              // 512 % 8 == 0 -> bijective
    const int lb = (hw & 7) * 64 + (hw >> 3);
    const int b  = lb >> 1;
    const int s  = lb & 1;

    const int tid  = threadIdx.x;
    const int lane = tid & 63;
    const int wid  = tid >> 6;

    // staging: 4 threads per row, 8 floats each; rows r and r+128
    const int  srow = tid >> 2;             // 0..127
    const int  scol = (tid & 3) << 3;       // 0,8,16,24
    const int  row1 = srow + 128;           // 128..255
    const bool r1st = row1 < 208;           // staged at all
    const bool r1v  = row1 < TT;            // real data
    const float* zp0 = z + ((size_t)b * TT + srow) * DD + scol;
    const float* zp1 = z + ((size_t)b * TT + row1) * DD + scol;

    f32x4 acc[13];
#pragma unroll
    for (int j = 0; j < 13; ++j) acc[j] = (f32x4){0.f, 0.f, 0.f, 0.f};

    float z2p0 = 0.f, z2p1 = 0.f;

    // prologue: stage slab 0 into buffer 0
    {
        float4 a0 = *(const float4*)(zp0);
        float4 a1 = *(const float4*)(zp0 + 4);
        z2p0 += sq8(a0, a1);
        *(bf16x8*)&Zt[0][srow][scol] = pack8(a0, a1);
        if (r1st) {
            float4 b0 = make_float4(0.f,0.f,0.f,0.f), b1 = make_float4(0.f,0.f,0.f,0.f);
            if (r1v) { b0 = *(const float4*)(zp1); b1 = *(const float4*)(zp1 + 4); }
            z2p1 += sq8(b0, b1);
            *(bf16x8*)&Zt[0][row1][scol] = pack8(b0, b1);
        }
    }

    int arow = s * 128 + (wid << 4) + (lane & 15);
    if (arow > 207) arow = 207;             // strip-1 waves 5..7: garbage, discarded
    const int koff = (lane >> 4) << 3;

    int cur = 0;
#pragma unroll 1
    for (int ks = 0; ks < NKS; ++ks) {
        __syncthreads();
        const bool more = (ks + 1) < NKS;

        float4 a0, a1, b0, b1;
        a0 = a1 = b0 = b1 = make_float4(0.f,0.f,0.f,0.f);
        if (more) {
            const float* p0 = zp0 + (ks + 1) * BK;
            a0 = *(const float4*)(p0);
            a1 = *(const float4*)(p0 + 4);
            if (r1v) {
                const float* p1 = zp1 + (ks + 1) * BK;
                b0 = *(const float4*)(p1);
                b1 = *(const float4*)(p1 + 4);
            }
        }

        bf16x8 af = *(const bf16x8*)&Zt[cur][arow][koff];
#pragma unroll
        for (int j = 0; j < 13; ++j) {
            bf16x8 bfr = *(const bf16x8*)&Zt[cur][(j << 4) + (lane & 15)][koff];
            acc[j] = __builtin_amdgcn_mfma_f32_16x16x32_bf16(af, bfr, acc[j], 0, 0, 0);
        }

        if (more) {
            z2p0 += sq8(a0, a1);
            *(bf16x8*)&Zt[cur ^ 1][srow][scol] = pack8(a0, a1);
            if (r1st) {
                z2p1 += sq8(b0, b1);
                *(bf16x8*)&Zt[cur ^ 1][row1][scol] = pack8(b0, b1);
            }
        }
        cur ^= 1;
    }

    // z2: reduce the 4 threads sharing each row; only strip 0 writes
    float zz0 = z2p0 + __shfl_xor(z2p0, 1); zz0 += __shfl_xor(zz0, 2);
    float zz1 = z2p1 + __shfl_xor(z2p1, 1); zz1 += __shfl_xor(zz1, 2);
    if (s == 0 && (tid & 3) == 0) {
        z2g[b * TT + srow] = zz0;                    // srow 0..127 always valid
        if (r1v) z2g[b * TT + row1] = zz1;
    }

    // store G: C/D layout col = lane&15, row = (lane>>4)*4 + reg
    const int l15 = lane & 15;
    const int lq  = lane >> 4;
#pragma unroll
    for (int j = 0; j < 13; ++j) {
        const int u = (j << 4) + l15;
        if (u >= TT) continue;
#pragma unroll
        for (int r = 0; r < 4; ++r) {
            const int t = s * 128 + (wid << 4) + (lq << 2) + r;
            if (t < TT) G[((size_t)b * TT + t) * TT + u] = acc[j][r];
        }
    }
}

// ---------------- Kernel B: stream gt_dT, accumulate loss ----------------

#define BTH   256
#define BGRID 2048

__global__ __launch_bounds__(BTH)
void loss_kernel(const float4* __restrict__ gt4,
                 const float* __restrict__ G,
                 const float* __restrict__ z2g,
                 const float* __restrict__ sigma,
                 float* __restrict__ partials)
{
    const int tid = threadIdx.x;
    const float4 sg = *(const float4*)sigma;
    const float c0 = 0.5f / (sg.x * sg.x);
    const float c1 = 0.5f / (sg.y * sg.y);
    const float c2 = 0.5f / (sg.z * sg.z);
    const float c3 = 0.5f / (sg.w * sg.w);

    const unsigned total  = NB * TTT;       // 9,834,496 quads
    const unsigned stride = BTH * BGRID;
    float lsum = 0.f;

    for (unsigned q = blockIdx.x * BTH + tid; q < total; q += stride) {
        const unsigned b  = q / TTT;
        const unsigned rr = q - b * TTT;
        const unsigned t  = rr / TT;
        const unsigned u  = rr - t * TT;

        const float4 g   = gt4[q];
        const float  Gtu = G[q];
        const float  z2t = z2g[b * TT + t];
        const float  z2u = z2g[b * TT + u];

        const float sS = g.x*g.x*c0 + g.y*g.y*c1 + g.z*g.z*c2 + g.w*g.w*c3;
        lsum += __expf(-sS) * (z2t + z2u - 2.f * Gtu);
    }

#pragma unroll
    for (int off = 32; off > 0; off >>= 1) lsum += __shfl_xor(lsum, off);

    __shared__ float red[BTH / 64];
    if ((tid & 63) == 0) red[tid >> 6] = lsum;
    __syncthreads();
    if (tid == 0) {
        float s = 0.f;
#pragma unroll
        for (int w = 0; w < BTH / 64; ++w) s += red[w];
        partials[blockIdx.x] = s;
    }
}

// ---------------- Kernel C: finalize ----------------

__global__ __launch_bounds__(256)
void finalize_kernel(const float* __restrict__ partials, float* __restrict__ out)
{
    const int tid = threadIdx.x;
    float s = 0.f;
#pragma unroll
    for (int k = 0; k < BGRID / 256; ++k) s += partials[tid + k * 256];
#pragma unroll
    for (int off = 32; off > 0; off >>= 1) s += __shfl_xor(s, off);
    __shared__ float red[4];
    if ((tid & 63) == 0) red[tid >> 6] = s;
    __syncthreads();
    if (tid == 0) {
        float tot = red[0] + red[1] + red[2] + red[3];
        out[0] = tot * (1.0f / ((float)NB * (float)TT * (float)TT));
    }
}

// ---------------- Fallback: round-1 fused kernel (ws too small) ----------------

#define TP  208
#define NW  13
#define NTH (NW * 64)

__global__ __launch_bounds__(NTH)
void patch_loss_fused(const float* __restrict__ z,
                      const float* __restrict__ gt,
                      const float* __restrict__ sigma,
                      float* __restrict__ out)
{
    __shared__ __bf16 Zt[2][TP][BK];
    __shared__ float z2s[TP];
    __shared__ float red[NW];

    const int b    = blockIdx.x;
    const int tid  = threadIdx.x;
    const int lane = tid & 63;
    const int wid  = tid >> 6;

    const int  srow = tid >> 2;
    const int  scol = (tid & 3) << 3;
    const bool srv  = srow < TT;
    const float* zrow = z + ((size_t)b * TT + srow) * DD + scol;

    f32x4 acc[NW];
#pragma unroll
    for (int j = 0; j < NW; ++j) acc[j] = (f32x4){0.f, 0.f, 0.f, 0.f};
    float z2p = 0.f;
    {
        float4 r0 = make_float4(0.f,0.f,0.f,0.f), r1 = make_float4(0.f,0.f,0.f,0.f);
        if (srv) { r0 = *(const float4*)(zrow); r1 = *(const float4*)(zrow + 4); }
        z2p += sq8(r0, r1);
        *(bf16x8*)&Zt[0][srow][scol] = pack8(r0, r1);
    }
    const int arow = (wid << 4) + (lane & 15);
    const int koff = (lane >> 4) << 3;
    int cur = 0;
#pragma unroll 1
    for (int ks = 0; ks < NKS; ++ks) {
        __syncthreads();
        const bool more = (ks + 1) < NKS;
        float4 r0 = make_float4(0.f,0.f,0.f,0.f), r1 = make_float4(0.f,0.f,0.f,0.f);
        if (more && srv) {
            const float* p = zrow + (ks + 1) * BK;
            r0 = *(const float4*)(p); r1 = *(const float4*)(p + 4);
        }
        bf16x8 af = *(const bf16x8*)&Zt[cur][arow][koff];
#pragma unroll
        for (int j = 0; j < NW; ++j) {
            bf16x8 bfr = *(const bf16x8*)&Zt[cur][(j << 4) + (lane & 15)][koff];
            acc[j] = __builtin_amdgcn_mfma_f32_16x16x32_bf16(af, bfr, acc[j], 0, 0, 0);
        }
        if (more) {
            z2p += sq8(r0, r1);
            *(bf16x8*)&Zt[cur ^ 1][srow][scol] = pack8(r0, r1);
        }
        cur ^= 1;
    }
    float zz = z2p + __shfl_xor(z2p, 1);
    zz += __shfl_xor(zz, 2);
    if ((tid & 3) == 0) z2s[srow] = srv ? zz : 0.f;
    __syncthreads();

    const float4 sg = *(const float4*)sigma;
    const float c0 = 0.5f / (sg.x * sg.x);
    const float c1 = 0.5f / (sg.y * sg.y);
    const float c2 = 0.5f / (sg.z * sg.z);
    const float c3 = 0.5f / (sg.w * sg.w);
    const int l15 = lane & 15;
    const int lq  = lane >> 4;
    int   trow[4]; float z2t[4]; size_t tbase[4];
#pragma unroll
    for (int r = 0; r < 4; ++r) {
        const int t = (wid << 4) + (lq << 2) + r;
        trow[r] = t; z2t[r] = z2s[t];
        tbase[r] = ((size_t)b * TT + t) * TT;
    }
    const float4* gtp = (const float4*)gt;
    float lsum = 0.f;
#pragma unroll
    for (int j = 0; j < NW; ++j) {
        const int  u  = (j << 4) + l15;
        const bool uv = u < TT;
        const float z2u = z2s[u];
        float4 dv[4];
#pragma unroll
        for (int r = 0; r < 4; ++r) {
            const bool v = uv && (trow[r] < TT);
            dv[r] = v ? gtp[tbase[r] + u] : make_float4(0.f,0.f,0.f,0.f);
        }
#pragma unroll
        for (int r = 0; r < 4; ++r) {
            const bool v = uv && (trow[r] < TT);
            if (v) {
                const float sS = dv[r].x*dv[r].x*c0 + dv[r].y*dv[r].y*c1
                               + dv[r].z*dv[r].z*c2 + dv[r].w*dv[r].w*c3;
                lsum += __expf(-sS) * (z2t[r] + z2u - 2.f * acc[j][r]);
            }
        }
    }
#pragma unroll
    for (int off = 32; off > 0; off >>= 1) lsum += __shfl_xor(lsum, off);
    if (lane == 0) red[wid] = lsum;
    __syncthreads();
    if (tid == 0) {
        float sum = 0.f;
#pragma unroll
        for (int w = 0; w < NW; ++w) sum += red[w];
        atomicAdd(out, sum * (1.0f / ((float)NB * (float)TT * (float)TT)));
    }
}

// ---------------- launch ----------------

extern "C" void kernel_launch(void* const* d_in, const int* in_sizes, int n_in,
                              void* d_out, int out_size, void* d_ws, size_t ws_size,
                              hipStream_t stream) {
    const float* z     = (const float*)d_in[0];
    const float* gt    = (const float*)d_in[1];
    const float* sigma = (const float*)d_in[2];
    float* out = (float*)d_out;

    const size_t G_elems  = (size_t)NB * TTT;            // 9,834,496 f32
    const size_t z2_elems = (size_t)NB * TT;             // 50,176 f32
    const size_t need = (G_elems + z2_elems + BGRID) * sizeof(float);   // ~39.5 MB

    if (ws_size >= need) {
        float* G        = (float*)d_ws;
        float* z2g      = G + G_elems;
        float* partials = z2g + z2_elems;

        gram_kernel<<<dim3(512), dim3(ATH), 0, stream>>>(z, G, z2g);
        loss_kernel<<<dim3(BGRID), dim3(BTH), 0, stream>>>(
            (const float4*)gt, G, z2g, sigma, partials);
        finalize_kernel<<<dim3(1), dim3(256), 0, stream>>>(partials, out);
    } else {
        hipMemsetAsync(out, 0, sizeof(float), stream);
        patch_loss_fused<<<dim3(NB), dim3(NTH), 0, stream>>>(z, gt, sigma, out);
    }
}

// Round 5
// 327.730 us; speedup vs baseline: 1.0070x; 1.0070x over previous
//
#include <hip/hip_runtime.h>
#include <hip/hip_bf16.h>

// PatchLoss fused v2.1 for MI355X (gfx950).  [resubmit — rounds 3/4 never ran]
//
// loss = (1/(B*T^2)) * sum_{b,t,u} w[b,t,u] * (z2[b,t] + z2[b,u] - 2*G[b,t,u])
//   w = exp(-sum_k gt_dT^2 / (2 sigma_k^2)),  G[b] = z_b z_b^T,  z2 = ||z_bt||^2
//
// Round-1 (fused, grid 256 = 1 block/CU): 117us, latency-bound (Mfma 5.5 /
// VALU 9.2 / HBM 17%, Occ 36% -> all idle). Round-2 (3-kernel via ws):
// ~125us kernel portion + 39MB G round-trip + 93us ws re-poison. This round:
// fused, grid 512 = 2 blocks/CU (b x 2 t-strips) so phase-1 (MFMA + z
// stream) of one block overlaps phase-2 (expf + gt stream) of its CU
// partner. Padded LDS (stride 40 elems = 20 banks) removes round-1's 4.5M
// bank conflicts. Phase 2 double-buffers its gt_dT loads (4 float4 in
// flight while computing previous 4). No workspace use.
//
// Traffic: z 154MB (x2 strips, partner L2-hot via XCD swizzle) + gt 157MB.

typedef __attribute__((ext_vector_type(8))) __bf16 bf16x8;
typedef __attribute__((ext_vector_type(4))) float f32x4;

#define NB   256
#define TT   196
#define DD   768
#define BK   32
#define NKS  (DD / BK)    // 24
#define ZPAD 40           // LDS row stride (elems): 80 B = 20 banks, conflict-free
#define NTH  512          // 8 waves

__device__ __forceinline__ bf16x8 pack8(const float4& a, const float4& b) {
    bf16x8 v;
    v[0] = (__bf16)a.x; v[1] = (__bf16)a.y; v[2] = (__bf16)a.z; v[3] = (__bf16)a.w;
    v[4] = (__bf16)b.x; v[5] = (__bf16)b.y; v[6] = (__bf16)b.z; v[7] = (__bf16)b.w;
    return v;
}
__device__ __forceinline__ float sq8(const float4& a, const float4& b) {
    return a.x*a.x + a.y*a.y + a.z*a.z + a.w*a.w
         + b.x*b.x + b.y*b.y + b.z*b.z + b.w*b.w;
}

__global__ __launch_bounds__(NTH)
void patch_loss_fused2(const float* __restrict__ z,
                       const float* __restrict__ gt,
                       const float* __restrict__ sigma,
                       float* __restrict__ out)
{
    __shared__ __bf16 Zt[2][208][ZPAD];   // 2 x 16.25 KB staging
    __shared__ float z2s[208];
    __shared__ float red[8];

    // XCD swizzle (512 % 8 == 0, bijective): (b,0) and (b,1) on the same XCD.
    const int hw = blockIdx.x;
    const int lb = (hw & 7) * 64 + (hw >> 3);
    const int b  = lb >> 1;
    const int s  = lb & 1;
    const int nmf = 7 - s;                // MFMA-active waves: s=0 ->7, s=1 ->6

    const int tid  = threadIdx.x;
    const int lane = tid & 63;
    const int wid  = tid >> 6;

    // ---- staging: thread covers rows srow (0..127) and srow+128 (<208), 8 cols
    const int  srow = tid >> 2;           // 0..127  (always < TT)
    const int  scol = (tid & 3) << 3;     // 0,8,16,24
    const int  row1 = srow + 128;         // 128..255
    const bool r1st = row1 < 208;
    const bool r1v  = row1 < TT;
    const float* zp0 = z + ((size_t)b * TT + srow) * DD + scol;
    const float* zp1 = z + ((size_t)b * TT + row1) * DD + scol;

    f32x4 acc[13];
#pragma unroll
    for (int j = 0; j < 13; ++j) acc[j] = (f32x4){0.f, 0.f, 0.f, 0.f};

    float z2p0 = 0.f, z2p1 = 0.f;

    // prologue: stage K-slab 0 into buffer 0
    {
        float4 a0 = *(const float4*)(zp0);
        float4 a1 = *(const float4*)(zp0 + 4);
        z2p0 += sq8(a0, a1);
        *(bf16x8*)&Zt[0][srow][scol] = pack8(a0, a1);
        if (r1st) {
            float4 b0 = make_float4(0.f,0.f,0.f,0.f), b1 = make_float4(0.f,0.f,0.f,0.f);
            if (r1v) { b0 = *(const float4*)(zp1); b1 = *(const float4*)(zp1 + 4); }
            z2p1 += sq8(b0, b1);
            *(bf16x8*)&Zt[0][row1][scol] = pack8(b0, b1);
        }
    }

    // ---- MFMA addressing: A rows = s*112 + wid*16 + (lane&15)
    const int arow = s * 112 + (wid << 4) + (lane & 15);   // <= 207 for wid < nmf
    const int koff = (lane >> 4) << 3;

    int cur = 0;
#pragma unroll 1
    for (int ks = 0; ks < NKS; ++ks) {
        __syncthreads();
        const bool more = (ks + 1) < NKS;

        float4 a0, a1, b0, b1;
        a0 = a1 = b0 = b1 = make_float4(0.f,0.f,0.f,0.f);
        if (more) {
            const float* p0 = zp0 + (ks + 1) * BK;
            a0 = *(const float4*)(p0);
            a1 = *(const float4*)(p0 + 4);
            if (r1v) {
                const float* p1 = zp1 + (ks + 1) * BK;
                b0 = *(const float4*)(p1);
                b1 = *(const float4*)(p1 + 4);
            }
        }

        if (wid < nmf) {
            bf16x8 af = *(const bf16x8*)&Zt[cur][arow][koff];
#pragma unroll
            for (int j = 0; j < 13; ++j) {
                bf16x8 bfr = *(const bf16x8*)&Zt[cur][(j << 4) + (lane & 15)][koff];
                acc[j] = __builtin_amdgcn_mfma_f32_16x16x32_bf16(af, bfr, acc[j], 0, 0, 0);
            }
        }

        if (more) {
            z2p0 += sq8(a0, a1);
            *(bf16x8*)&Zt[cur ^ 1][srow][scol] = pack8(a0, a1);
            if (r1st) {
                z2p1 += sq8(b0, b1);
                *(bf16x8*)&Zt[cur ^ 1][row1][scol] = pack8(b0, b1);
            }
        }
        cur ^= 1;
    }

    // ---- z2: reduce 4 threads per row, publish all 208 rows (pad rows -> 0)
    float zz0 = z2p0 + __shfl_xor(z2p0, 1); zz0 += __shfl_xor(zz0, 2);
    float zz1 = z2p1 + __shfl_xor(z2p1, 1); zz1 += __shfl_xor(zz1, 2);
    if ((tid & 3) == 0) {
        z2s[srow] = zz0;
        if (r1st) z2s[row1] = r1v ? zz1 : 0.f;
    }
    __syncthreads();

    // ---- phase 2: stream gt_dT for this strip's t-rows, fold with register G
    const float4 sg = *(const float4*)sigma;
    const float c0 = 0.5f / (sg.x * sg.x);
    const float c1 = 0.5f / (sg.y * sg.y);
    const float c2 = 0.5f / (sg.z * sg.z);
    const float c3 = 0.5f / (sg.w * sg.w);

    const int l15 = lane & 15;
    const int lq  = lane >> 4;
    const float4 zero4 = make_float4(0.f, 0.f, 0.f, 0.f);

    float lsum = 0.f;
    if (wid < nmf) {
        // C/D layout: col = lane&15 (u), row = (lane>>4)*4 + reg (t offset)
        int   trow[4];
        float z2t[4];
        size_t tbase[4];
#pragma unroll
        for (int r = 0; r < 4; ++r) {
            const int t = s * 112 + (wid << 4) + (lq << 2) + r;
            trow[r]  = t;
            z2t[r]   = (t < TT) ? z2s[t] : 0.f;
            tbase[r] = ((size_t)b * TT + (t < TT ? t : 0)) * TT;
        }

        const float4* gtp = (const float4*)gt;

        // double-buffered gt stream: prefetch j+1 while computing j
        float4 dv[4];
#pragma unroll
        for (int r = 0; r < 4; ++r) {
            const bool v = (trow[r] < TT);                 // u = l15 < 16 <= TT
            dv[r] = v ? gtp[tbase[r] + l15] : zero4;
        }

#pragma unroll
        for (int j = 0; j < 13; ++j) {
            const int  u  = (j << 4) + l15;
            const bool uv = u < TT;
            const float z2u = uv ? z2s[u] : 0.f;

            float4 nv[4];
            if (j + 1 < 13) {
                const int  un  = u + 16;
                const bool uvn = un < TT;
#pragma unroll
                for (int r = 0; r < 4; ++r) {
                    const bool vn = uvn && (trow[r] < TT);
                    nv[r] = vn ? gtp[tbase[r] + un] : zero4;
                }
            }

#pragma unroll
            for (int r = 0; r < 4; ++r) {
                const bool v = uv && (trow[r] < TT);
                if (v) {
                    const float sS = dv[r].x*dv[r].x*c0 + dv[r].y*dv[r].y*c1
                                   + dv[r].z*dv[r].z*c2 + dv[r].w*dv[r].w*c3;
                    lsum += __expf(-sS) * (z2t[r] + z2u - 2.f * acc[j][r]);
                }
            }

            if (j + 1 < 13) {
#pragma unroll
                for (int r = 0; r < 4; ++r) dv[r] = nv[r];
            }
        }
    }

    // ---- reduce: wave shuffle -> LDS -> one atomic per block
#pragma unroll
    for (int off = 32; off > 0; off >>= 1) lsum += __shfl_xor(lsum, off);
    if (lane == 0) red[wid] = lsum;
    __syncthreads();
    if (tid == 0) {
        float t = 0.f;
#pragma unroll
        for (int w = 0; w < 8; ++w) t += red[w];
        atomicAdd(out, t * (1.0f / ((float)NB * (float)TT * (float)TT)));
    }
}

extern "C" void kernel_launch(void* const* d_in, const int* in_sizes, int n_in,
                              void* d_out, int out_size, void* d_ws, size_t ws_size,
                              hipStream_t stream) {
    const float* z     = (const float*)d_in[0];
    const float* gt    = (const float*)d_in[1];
    const float* sigma = (const float*)d_in[2];
    float* out = (float*)d_out;

    hipMemsetAsync(out, 0, sizeof(float), stream);   // harness poisons d_out
    patch_loss_fused2<<<dim3(512), dim3(NTH), 0, stream>>>(z, gt, sigma, out);
}